// Round 7
// baseline (419.086 us; speedup 1.0000x reference)
//
#include <hip/hip_runtime.h>

#define NN 50000
#define NE 800000
#define NS 5000
#define CAP 64

typedef float f32x4 __attribute__((ext_vector_type(4)));
typedef short s16x8 __attribute__((ext_vector_type(8)));
typedef unsigned int uint;

// ---------------- bf16 helpers ----------------

__device__ inline float bf2f(uint u16) {
  return __uint_as_float(u16 << 16);
}
__device__ inline unsigned short f2bf(float f) {
  uint x = __float_as_uint(f);
  uint r = (x + 0x7fffu + ((x >> 16) & 1u)) >> 16;  // RNE
  return (unsigned short)r;
}
__device__ inline uint pack_bf2(float lo, float hi) {
  return (uint)f2bf(lo) | ((uint)f2bf(hi) << 16);
}

// ---------------- init: counters + winner arrays ----------------

__global__ void k_init(int* __restrict__ cnt1, int* __restrict__ cnt2,
                       int* __restrict__ winA, int* __restrict__ winB) {
  int i = blockIdx.x * blockDim.x + threadIdx.x;
  if (i < NN) { cnt1[i] = 0; cnt2[i] = 0; winA[i] = -1; winB[i] = -1; }
}

__global__ void k_win_scan(const int* __restrict__ seeds, int* __restrict__ winA,
                           int* __restrict__ winB) {
  int i = blockIdx.x * blockDim.x + threadIdx.x;
  if (i < NS) {
    atomicMax(&winA[seeds[i]], i);
    atomicMax(&winB[seeds[NS + i]], i);
  }
}

// ---------------- bucket scatter (eid only): one edge pass, both graphs ----------------

__global__ void k_bucket(const int* __restrict__ ei1, const int* __restrict__ ei2,
                         int* __restrict__ cnt1, int* __restrict__ cnt2,
                         uint* __restrict__ bk1, uint* __restrict__ bk2) {
  int i = blockIdx.x * blockDim.x + threadIdx.x;
  if (i >= 2 * NE) return;
  int g = i >= NE;
  int j = g ? i - NE : i;
  const int* ei = g ? ei2 : ei1;
  int* cnt = g ? cnt2 : cnt1;
  uint* bk = g ? bk2 : bk1;
  int d = ei[NE + j];
  int r = atomicAdd(&cnt[d], 1);
  if (r < CAP) bk[(size_t)d * CAP + r] = (uint)j;
}

// dis[i] = rsqrt(1 + sum of segment weights), both graphs
__global__ void k_deg_dis(const int* __restrict__ cnt1, const uint* __restrict__ bk1,
                          const float* __restrict__ ew1,
                          const int* __restrict__ cnt2, const uint* __restrict__ bk2,
                          const float* __restrict__ ew2, float* __restrict__ dis) {
  int i = blockIdx.x * blockDim.x + threadIdx.x;
  if (i >= 2 * NN) return;
  int g = i >= NN;
  int node = g ? i - NN : i;
  const int* cnt = g ? cnt2 : cnt1;
  const uint* bk = g ? bk2 : bk1;
  const float* ew = g ? ew2 : ew1;
  int m = cnt[node]; if (m > CAP) m = CAP;
  float s = 1.0f;  // self-loop weight
  const uint* p = &bk[(size_t)node * CAP];
  for (int e = 0; e < m; ++e) s += ew[p[e]];
  dis[i] = rsqrtf(s);
}

// ---------------- MFMA GEMM (dual-graph): Y(bf16) = X @ W ----------------
// 64 rows/block, 4 waves x 16 rows, whole K=128 staged bf16 in LDS, XOR-swizzled.

template<int FOUT, bool INBF16>
__global__ __launch_bounds__(256) void k_gemm2(const void* __restrict__ X1,
                                               const void* __restrict__ X2,
                                               const float* __restrict__ Wa,
                                               const float* __restrict__ Wb,
                                               unsigned short* __restrict__ Y1,
                                               unsigned short* __restrict__ Y2,
                                               int nbpg) {
  constexpr int NT = FOUT / 16;
  __shared__ uint sX[64 * 64];     // [row][k2] bf16x2, swizzled
  __shared__ uint sW[FOUT * 64];   // [col][k2] bf16x2 (transposed), swizzled
  const int g = blockIdx.x >= nbpg;
  const int bid = blockIdx.x - (g ? nbpg : 0);
  const void* X = g ? X2 : X1;
  const float* W = g ? Wb : Wa;
  unsigned short* Y = g ? Y2 : Y1;
  const int tid = threadIdx.x;
  const int lane = tid & 63;
  const int wid = tid >> 6;
  const int row0 = bid * 64;

  // --- stage X ---
  if (INBF16) {
    const uint* Xu = (const uint*)X;   // row stride 64 uints
#pragma unroll
    for (int it = 0; it < 4; ++it) {
      int idx = it * 256 + tid;        // 64 rows * 16 uint4-slots
      int r = idx >> 4;
      int q = idx & 15;
      int row = row0 + r;
      uint4 v = make_uint4(0u, 0u, 0u, 0u);
      if (row < NN) v = *(const uint4*)&Xu[(size_t)row * 64 + q * 4];
      int sw = (r & 7) << 2;
      sX[r * 64 + ((q * 4 + 0) ^ sw)] = v.x;
      sX[r * 64 + ((q * 4 + 1) ^ sw)] = v.y;
      sX[r * 64 + ((q * 4 + 2) ^ sw)] = v.z;
      sX[r * 64 + ((q * 4 + 3) ^ sw)] = v.w;
    }
  } else {
    const float* Xf = (const float*)X;
#pragma unroll
    for (int it = 0; it < 8; ++it) {
      int idx = it * 256 + tid;        // 64 rows * 32 float4-slots
      int r = idx >> 5;
      int k4 = idx & 31;
      int row = row0 + r;
      float4 v = make_float4(0.f, 0.f, 0.f, 0.f);
      if (row < NN) v = *(const float4*)&Xf[(size_t)row * 128 + k4 * 4];
      int sw = (r & 7) << 2;
      int k2 = k4 * 2;
      sX[r * 64 + ((k2 + 0) ^ sw)] = pack_bf2(v.x, v.y);
      sX[r * 64 + ((k2 + 1) ^ sw)] = pack_bf2(v.z, v.w);
    }
  }

  // --- stage W transposed: sW[col][k2] ---
#pragma unroll
  for (int it = 0; it < FOUT / 16; ++it) {
    int idx = it * 256 + tid;          // 64 k2-slots * FOUT/4 col4-slots
    int k2 = idx / (FOUT / 4);
    int col4 = idx % (FOUT / 4);
    float4 a = *(const float4*)&W[(size_t)(2 * k2) * FOUT + col4 * 4];
    float4 b = *(const float4*)&W[(size_t)(2 * k2 + 1) * FOUT + col4 * 4];
    const float* ap = &a.x;
    const float* bp = &b.x;
#pragma unroll
    for (int c = 0; c < 4; ++c) {
      int col = col4 * 4 + c;
      sW[col * 64 + (k2 ^ ((col & 7) << 2))] = pack_bf2(ap[c], bp[c]);
    }
  }
  __syncthreads();

  // --- MFMA ---
  f32x4 acc[NT];
#pragma unroll
  for (int t = 0; t < NT; ++t) acc[t] = (f32x4)(0.f);

  const int rt = (wid << 4) + (lane & 15);
  const int kg = lane >> 4;
#pragma unroll
  for (int ks = 0; ks < 4; ++ks) {
    int k2off = ks * 16 + kg * 4;
    s16x8 a = *(const s16x8*)&sX[rt * 64 + (k2off ^ ((rt & 7) << 2))];
#pragma unroll
    for (int t = 0; t < NT; ++t) {
      int col = t * 16 + (lane & 15);
      s16x8 b = *(const s16x8*)&sW[col * 64 + (k2off ^ ((col & 7) << 2))];
      acc[t] = __builtin_amdgcn_mfma_f32_16x16x32_bf16(a, b, acc[t], 0, 0, 0);
    }
  }

  // --- store C (bf16): col=lane&15, row=(lane>>4)*4+reg ---
  const int rbase = row0 + (wid << 4) + ((lane >> 4) << 2);
#pragma unroll
  for (int t = 0; t < NT; ++t) {
    int col = t * 16 + (lane & 15);
#pragma unroll
    for (int r = 0; r < 4; ++r) {
      int row = rbase + r;
      if (row < NN) Y[(size_t)row * FOUT + col] = f2bf(acc[t][r]);
    }
  }
}

// ---------------- fused bucket-gather aggregation (dual-graph, wave-cooperative) ----
// out[i] = relu?( dis_d * ( dis_d*y[i] + sum_e dis[s]*w*y[s] ) + b )

__device__ inline void bf8_fma(float* acc, uint4 v, float w) {
  acc[0] = fmaf(w, bf2f(v.x & 0xffffu), acc[0]);
  acc[1] = fmaf(w, bf2f(v.x >> 16), acc[1]);
  acc[2] = fmaf(w, bf2f(v.y & 0xffffu), acc[2]);
  acc[3] = fmaf(w, bf2f(v.y >> 16), acc[3]);
  acc[4] = fmaf(w, bf2f(v.z & 0xffffu), acc[4]);
  acc[5] = fmaf(w, bf2f(v.z >> 16), acc[5]);
  acc[6] = fmaf(w, bf2f(v.w & 0xffffu), acc[6]);
  acc[7] = fmaf(w, bf2f(v.w >> 16), acc[7]);
}

template<int F, bool RELU, bool OUTBF16>
__global__ __launch_bounds__(256) void k_gather2(
    const int* __restrict__ cnt1, const uint* __restrict__ bk1,
    const int* __restrict__ ei1, const float* __restrict__ ew1,
    const uint* __restrict__ y1, const float* __restrict__ dis1,
    const float* __restrict__ bias1, void* __restrict__ out1,
    const int* __restrict__ cnt2, const uint* __restrict__ bk2,
    const int* __restrict__ ei2, const float* __restrict__ ew2,
    const uint* __restrict__ y2, const float* __restrict__ dis2,
    const float* __restrict__ bias2, void* __restrict__ out2, int nbpg) {
  constexpr int TPN = F / 8;        // threads per node (8 feats each)
  constexpr int NPB = 256 / TPN;
  constexpr int RS = F / 2;         // row stride in uints
  const int g = blockIdx.x >= nbpg;
  const int bid = blockIdx.x - (g ? nbpg : 0);
  const int* cnt = g ? cnt2 : cnt1;
  const uint* bk = g ? bk2 : bk1;
  const int* ei = g ? ei2 : ei1;
  const float* ew = g ? ew2 : ew1;
  const uint* y = g ? y2 : y1;
  const float* dis = g ? dis2 : dis1;
  const float* bias = g ? bias2 : bias1;
  void* out = g ? out2 : out1;

  int node = bid * NPB + threadIdx.x / TPN;
  int lane = threadIdx.x % TPN;
  if (node >= NN) return;
  const int c0 = lane * 4;

  const float dd = dis[node];
  float acc[8];
  {
    uint4 sv = *(const uint4*)&y[(size_t)node * RS + c0];
    acc[0] = dd * bf2f(sv.x & 0xffffu); acc[1] = dd * bf2f(sv.x >> 16);
    acc[2] = dd * bf2f(sv.y & 0xffffu); acc[3] = dd * bf2f(sv.y >> 16);
    acc[4] = dd * bf2f(sv.z & 0xffffu); acc[5] = dd * bf2f(sv.z >> 16);
    acc[6] = dd * bf2f(sv.w & 0xffffu); acc[7] = dd * bf2f(sv.w >> 16);
  }
  const uint* bkrow = &bk[(size_t)node * CAP];
  int m = cnt[node]; if (m > CAP) m = CAP;

  // full batches of TPN edges: lane e loads edge meta, shfl-broadcast to group
  int base = 0;
  for (; base + TPN <= m; base += TPN) {
    uint eid = bkrow[base + lane];       // coalesced within group
    int s = ei[eid];
    float wv = ew[eid] * dis[s];
#pragma unroll
    for (int b = 0; b < TPN; ++b) {
      int sb = __shfl(s, b, TPN);
      float wb = __shfl(wv, b, TPN);
      uint4 v = *(const uint4*)&y[(size_t)sb * RS + c0];
      bf8_fma(acc, v, wb);
    }
  }
  // tail
  int rem = m - base;
  if (rem > 0) {
    int s = 0; float wv = 0.f;
    if (lane < rem) {
      uint eid = bkrow[base + lane];
      s = ei[eid];
      wv = ew[eid] * dis[s];
    }
    for (int b = 0; b < rem; ++b) {
      int sb = __shfl(s, b, TPN);
      float wb = __shfl(wv, b, TPN);
      uint4 v = *(const uint4*)&y[(size_t)sb * RS + c0];
      bf8_fma(acc, v, wb);
    }
  }

  float4 b0 = *(const float4*)&bias[lane * 8];
  float4 b1 = *(const float4*)&bias[lane * 8 + 4];
  float r0[8];
  r0[0] = fmaf(dd, acc[0], b0.x); r0[1] = fmaf(dd, acc[1], b0.y);
  r0[2] = fmaf(dd, acc[2], b0.z); r0[3] = fmaf(dd, acc[3], b0.w);
  r0[4] = fmaf(dd, acc[4], b1.x); r0[5] = fmaf(dd, acc[5], b1.y);
  r0[6] = fmaf(dd, acc[6], b1.z); r0[7] = fmaf(dd, acc[7], b1.w);
  if (RELU) {
#pragma unroll
    for (int j = 0; j < 8; ++j) r0[j] = fmaxf(r0[j], 0.f);
  }
  if (OUTBF16) {
    uint4 o;
    o.x = pack_bf2(r0[0], r0[1]); o.y = pack_bf2(r0[2], r0[3]);
    o.z = pack_bf2(r0[4], r0[5]); o.w = pack_bf2(r0[6], r0[7]);
    *(uint4*)&((uint*)out)[(size_t)node * RS + c0] = o;
  } else {
    float4 o0 = make_float4(r0[0], r0[1], r0[2], r0[3]);
    float4 o1 = make_float4(r0[4], r0[5], r0[6], r0[7]);
    *(float4*)&((float*)out)[(size_t)node * F + lane * 8] = o0;
    *(float4*)&((float*)out)[(size_t)node * F + lane * 8 + 4] = o1;
  }
}

// ---------------- seed cross-injection on bf16 h (numpy last-write-wins) ----------------

__global__ void k_seed_gather(const int* __restrict__ seeds, const uint* __restrict__ h1,
                              const uint* __restrict__ h2, uint* __restrict__ tmpA,
                              uint* __restrict__ tmpB) {
  int i = blockIdx.x;
  int f = threadIdx.x;  // 64 packed uints per row
  int s0 = seeds[i];
  int s1 = seeds[NS + i];
  tmpA[(size_t)i * 64 + f] = h2[(size_t)s1 * 64 + f];
  tmpB[(size_t)i * 64 + f] = h1[(size_t)s0 * 64 + f];
}

__global__ void k_seed_apply(const int* __restrict__ seeds, const int* __restrict__ winA,
                             const int* __restrict__ winB, const uint* __restrict__ tmpA,
                             const uint* __restrict__ tmpB, uint* __restrict__ h1,
                             uint* __restrict__ h2) {
  int i = blockIdx.x;
  int f = threadIdx.x;
  int s0 = seeds[i];
  int s1 = seeds[NS + i];
  if (winA[s0] == i) {
    uint a = h1[(size_t)s0 * 64 + f];
    uint b = tmpA[(size_t)i * 64 + f];
    h1[(size_t)s0 * 64 + f] = pack_bf2(bf2f(a & 0xffffu) + bf2f(b & 0xffffu),
                                       bf2f(a >> 16) + bf2f(b >> 16));
  }
  if (winB[s1] == i) {
    uint a = h2[(size_t)s1 * 64 + f];
    uint b = tmpB[(size_t)i * 64 + f];
    h2[(size_t)s1 * 64 + f] = pack_bf2(bf2f(a & 0xffffu) + bf2f(b & 0xffffu),
                                       bf2f(a >> 16) + bf2f(b >> 16));
  }
}

// ---------------- launcher ----------------

extern "C" void kernel_launch(void* const* d_in, const int* in_sizes, int n_in,
                              void* d_out, int out_size, void* d_ws, size_t ws_size,
                              hipStream_t stream) {
  const float* x1  = (const float*)d_in[0];
  const int*   ei1 = (const int*)d_in[1];
  const float* ew1 = (const float*)d_in[2];
  const float* x2  = (const float*)d_in[3];
  const int*   ei2 = (const int*)d_in[4];
  const float* ew2 = (const float*)d_in[5];
  const int*   sds = (const int*)d_in[6];
  const float* W1  = (const float*)d_in[7];
  const float* b1  = (const float*)d_in[8];
  const float* W2  = (const float*)d_in[9];
  const float* b2  = (const float*)d_in[10];
  const float* W3  = (const float*)d_in[11];
  const float* b3  = (const float*)d_in[12];

  float* o1 = (float*)d_out;
  float* o2 = o1 + (size_t)NN * 64;

  // workspace layout (4-byte units), ~78 MB total
  float* dis  = (float*)d_ws;                   // 2*NN  (dis1 | dis2)
  uint*  yb1  = (uint*)(dis + 2 * NN);          // NN*64 (bf16x2)
  uint*  yb2  = yb1 + (size_t)NN * 64;          // NN*64
  uint*  h1   = yb2 + (size_t)NN * 64;          // NN*64 (bf16x2)
  uint*  h2   = h1 + (size_t)NN * 64;           // NN*64
  int*   winA = (int*)(h2 + (size_t)NN * 64);   // NN
  int*   winB = winA + NN;                      // NN
  int*   cnt1 = winB + NN;                      // NN
  int*   cnt2 = cnt1 + NN;                      // NN
  uint*  bk1  = (uint*)(cnt2 + NN);             // NN*CAP
  uint*  bk2  = bk1 + (size_t)NN * CAP;         // NN*CAP
  // tmpA/tmpB alias yb1 (dead between layer-1 gather and layer-2 gemm)
  uint*  tmpA = yb1;                            // NS*64
  uint*  tmpB = tmpA + (size_t)NS * 64;         // NS*64

  const int B = 256;
  const int gN = (NN + B - 1) / B;

  // 1. init counters + winners
  k_init<<<gN, B, 0, stream>>>(cnt1, cnt2, winA, winB);
  // 2. seed winner scan
  k_win_scan<<<(NS + B - 1) / B, B, 0, stream>>>(sds, winA, winB);
  // 3. bucket scatter (eid only), both graphs
  k_bucket<<<(2 * NE + B - 1) / B, B, 0, stream>>>(ei1, ei2, cnt1, cnt2, bk1, bk2);
  // 4. dis from bucket weights, both graphs
  k_deg_dis<<<(2 * NN + B - 1) / B, B, 0, stream>>>(cnt1, bk1, ew1, cnt2, bk2, ew2, dis);

  const int gemm_bpg = (NN + 63) / 64;
  const int ga128bpg = (NN * 16 + B - 1) / B;   // TPN=16
  const int ga64bpg  = (NN * 8 + B - 1) / B;    // TPN=8

  // 5. layer-1 GEMMs (f32 in, bf16 out), both graphs
  k_gemm2<128, false><<<2 * gemm_bpg, B, 0, stream>>>(
      x1, x2, W1, W2, (unsigned short*)yb1, (unsigned short*)yb2, gemm_bpg);
  // 6. layer-1 gathers -> h (bf16), both graphs
  k_gather2<128, true, true><<<2 * ga128bpg, B, 0, stream>>>(
      cnt1, bk1, ei1, ew1, yb1, dis, b1, h1,
      cnt2, bk2, ei2, ew2, yb2, dis + NN, b2, h2, ga128bpg);
  // 7-8. seed cross-injection
  k_seed_gather<<<NS, 64, 0, stream>>>(sds, h1, h2, tmpA, tmpB);
  k_seed_apply<<<NS, 64, 0, stream>>>(sds, winA, winB, tmpA, tmpB, h1, h2);
  // 9. layer-2 GEMMs (bf16 in, shared W3), both graphs
  k_gemm2<64, true><<<2 * gemm_bpg, B, 0, stream>>>(
      h1, h2, W3, W3, (unsigned short*)yb1, (unsigned short*)yb2, gemm_bpg);
  // 10. layer-2 gathers -> o (f32), both graphs
  k_gather2<64, false, false><<<2 * ga64bpg, B, 0, stream>>>(
      cnt1, bk1, ei1, ew1, yb1, dis, b3, o1,
      cnt2, bk2, ei2, ew2, yb2, dis + NN, b3, o2, ga64bpg);
}

// Round 8
// 197.123 us; speedup vs baseline: 2.1260x; 2.1260x over previous
//
#include <hip/hip_runtime.h>

#define NN 50000
#define NE 800000
#define NS 5000
#define CAP 64
#define NBIN 196        // ceil(NN/256)
#define BCAP 4608       // per-bin record capacity (mean 4096, +8 sigma)
#define TILE 2048       // edges per k_part block

typedef float f32x4 __attribute__((ext_vector_type(4)));
typedef short s16x8 __attribute__((ext_vector_type(8)));
typedef unsigned int uint;

// ---------------- bf16 helpers ----------------

__device__ inline float bf2f(uint u16) {
  return __uint_as_float(u16 << 16);
}
__device__ inline unsigned short f2bf(float f) {
  uint x = __float_as_uint(f);
  uint r = (x + 0x7fffu + ((x >> 16) & 1u)) >> 16;  // RNE
  return (unsigned short)r;
}
__device__ inline uint pack_bf2(float lo, float hi) {
  return (uint)f2bf(lo) | ((uint)f2bf(hi) << 16);
}

// ---------------- init: bin cursors + winner arrays ----------------

__global__ void k_init(int* __restrict__ bin_cur, int* __restrict__ winA,
                       int* __restrict__ winB) {
  int i = blockIdx.x * blockDim.x + threadIdx.x;
  if (i < NN) { winA[i] = -1; winB[i] = -1; }
  if (i < 2 * NBIN) bin_cur[i] = 0;
}

__global__ void k_win_scan(const int* __restrict__ seeds, int* __restrict__ winA,
                           int* __restrict__ winB) {
  int i = blockIdx.x * blockDim.x + threadIdx.x;
  if (i < NS) {
    atomicMax(&winA[seeds[i]], i);
    atomicMax(&winB[seeds[NS + i]], i);
  }
}

// ---------------- pass 1: bin partition (dual-graph) ----------------
// records: (src | dst_local<<16, w) appended into fixed per-bin regions.

__global__ __launch_bounds__(256) void k_part(const int* __restrict__ ei1,
                                              const float* __restrict__ ew1,
                                              const int* __restrict__ ei2,
                                              const float* __restrict__ ew2,
                                              int* __restrict__ bin_cur,
                                              uint2* __restrict__ rec, int ntiles) {
  __shared__ int hcnt[NBIN];
  __shared__ int hbase[NBIN];
  __shared__ int hoff[NBIN];
  const int g = blockIdx.x >= ntiles;
  const int t0 = (g ? blockIdx.x - ntiles : blockIdx.x) * TILE;
  const int* ei = g ? ei2 : ei1;
  const float* ew = g ? ew2 : ew1;
  for (int i = threadIdx.x; i < NBIN; i += 256) { hcnt[i] = 0; hoff[i] = 0; }
  __syncthreads();

  int dst[8];
#pragma unroll
  for (int k = 0; k < 8; ++k) {
    int e = t0 + k * 256 + threadIdx.x;
    int d = (e < NE) ? ei[NE + e] : -1;
    dst[k] = d;
    if (d >= 0) atomicAdd(&hcnt[d >> 8], 1);
  }
  __syncthreads();
  for (int i = threadIdx.x; i < NBIN; i += 256) {
    int c = hcnt[i];
    hbase[i] = (c > 0) ? atomicAdd(&bin_cur[g * NBIN + i], c) : 0;
  }
  __syncthreads();
#pragma unroll
  for (int k = 0; k < 8; ++k) {
    int e = t0 + k * 256 + threadIdx.x;
    int d = dst[k];
    if (d >= 0) {
      int b = d >> 8;
      int r = atomicAdd(&hoff[b], 1);
      int pos = hbase[b] + r;
      if (pos < BCAP) {
        uint meta = (uint)ei[e] | ((uint)(d & 255) << 16);
        rec[((size_t)(g * NBIN + b)) * BCAP + pos] =
            make_uint2(meta, __float_as_uint(ew[e]));
      }
    }
  }
}

// ---------------- pass 2: bin -> node buckets + cnt + dis ----------------
// one block per (graph, bin): exclusive owner of a 128KB bucket region.

__global__ __launch_bounds__(256) void k_fill(const int* __restrict__ bin_cur,
                                              const uint2* __restrict__ rec,
                                              uint2* __restrict__ bk1,
                                              uint2* __restrict__ bk2,
                                              int* __restrict__ cnt1,
                                              int* __restrict__ cnt2,
                                              float* __restrict__ dis) {
  __shared__ int lcnt[256];
  __shared__ float wsum[256];
  const int b = blockIdx.x % NBIN;
  const int g = blockIdx.x / NBIN;
  uint2* bk = g ? bk2 : bk1;
  int* cnt = g ? cnt2 : cnt1;
  lcnt[threadIdx.x] = 0;
  wsum[threadIdx.x] = 1.0f;   // self-loop weight
  __syncthreads();
  int n = bin_cur[g * NBIN + b];
  if (n > BCAP) n = BCAP;
  const uint2* rbase = &rec[((size_t)(g * NBIN + b)) * BCAP];
  for (int i = threadIdx.x; i < n; i += 256) {
    uint2 rv = rbase[i];
    int dl = rv.x >> 16;
    uint s = rv.x & 0xffffu;
    int r = atomicAdd(&lcnt[dl], 1);
    atomicAdd(&wsum[dl], __uint_as_float(rv.y));
    if (r < CAP) bk[(size_t)((b << 8) + dl) * CAP + r] = make_uint2(s, rv.y);
  }
  __syncthreads();
  int node = (b << 8) + threadIdx.x;
  if (node < NN) {
    int m = lcnt[threadIdx.x];
    if (m > CAP) m = CAP;
    cnt[node] = m;
    dis[g * NN + node] = rsqrtf(wsum[threadIdx.x]);
  }
}

// ---------------- MFMA GEMM (dual-graph): Y(bf16) = X @ W ----------------
// 64 rows/block, 4 waves x 16 rows, whole K=128 staged bf16 in LDS, XOR-swizzled.

template<int FOUT, bool INBF16>
__global__ __launch_bounds__(256) void k_gemm2(const void* __restrict__ X1,
                                               const void* __restrict__ X2,
                                               const float* __restrict__ Wa,
                                               const float* __restrict__ Wb,
                                               unsigned short* __restrict__ Y1,
                                               unsigned short* __restrict__ Y2,
                                               int nbpg) {
  constexpr int NT = FOUT / 16;
  __shared__ uint sX[64 * 64];     // [row][k2] bf16x2, swizzled
  __shared__ uint sW[FOUT * 64];   // [col][k2] bf16x2 (transposed), swizzled
  const int g = blockIdx.x >= nbpg;
  const int bid = blockIdx.x - (g ? nbpg : 0);
  const void* X = g ? X2 : X1;
  const float* W = g ? Wb : Wa;
  unsigned short* Y = g ? Y2 : Y1;
  const int tid = threadIdx.x;
  const int lane = tid & 63;
  const int wid = tid >> 6;
  const int row0 = bid * 64;

  // --- stage X ---
  if (INBF16) {
    const uint* Xu = (const uint*)X;   // row stride 64 uints
#pragma unroll
    for (int it = 0; it < 4; ++it) {
      int idx = it * 256 + tid;        // 64 rows * 16 uint4-slots
      int r = idx >> 4;
      int q = idx & 15;
      int row = row0 + r;
      uint4 v = make_uint4(0u, 0u, 0u, 0u);
      if (row < NN) v = *(const uint4*)&Xu[(size_t)row * 64 + q * 4];
      int sw = (r & 7) << 2;
      sX[r * 64 + ((q * 4 + 0) ^ sw)] = v.x;
      sX[r * 64 + ((q * 4 + 1) ^ sw)] = v.y;
      sX[r * 64 + ((q * 4 + 2) ^ sw)] = v.z;
      sX[r * 64 + ((q * 4 + 3) ^ sw)] = v.w;
    }
  } else {
    const float* Xf = (const float*)X;
#pragma unroll
    for (int it = 0; it < 8; ++it) {
      int idx = it * 256 + tid;        // 64 rows * 32 float4-slots
      int r = idx >> 5;
      int k4 = idx & 31;
      int row = row0 + r;
      float4 v = make_float4(0.f, 0.f, 0.f, 0.f);
      if (row < NN) v = *(const float4*)&Xf[(size_t)row * 128 + k4 * 4];
      int sw = (r & 7) << 2;
      int k2 = k4 * 2;
      sX[r * 64 + ((k2 + 0) ^ sw)] = pack_bf2(v.x, v.y);
      sX[r * 64 + ((k2 + 1) ^ sw)] = pack_bf2(v.z, v.w);
    }
  }

  // --- stage W transposed: sW[col][k2] ---
#pragma unroll
  for (int it = 0; it < FOUT / 16; ++it) {
    int idx = it * 256 + tid;          // 64 k2-slots * FOUT/4 col4-slots
    int k2 = idx / (FOUT / 4);
    int col4 = idx % (FOUT / 4);
    float4 a = *(const float4*)&W[(size_t)(2 * k2) * FOUT + col4 * 4];
    float4 b = *(const float4*)&W[(size_t)(2 * k2 + 1) * FOUT + col4 * 4];
    const float* ap = &a.x;
    const float* bp = &b.x;
#pragma unroll
    for (int c = 0; c < 4; ++c) {
      int col = col4 * 4 + c;
      sW[col * 64 + (k2 ^ ((col & 7) << 2))] = pack_bf2(ap[c], bp[c]);
    }
  }
  __syncthreads();

  // --- MFMA ---
  f32x4 acc[NT];
#pragma unroll
  for (int t = 0; t < NT; ++t) acc[t] = (f32x4)(0.f);

  const int rt = (wid << 4) + (lane & 15);
  const int kg = lane >> 4;
#pragma unroll
  for (int ks = 0; ks < 4; ++ks) {
    int k2off = ks * 16 + kg * 4;
    s16x8 a = *(const s16x8*)&sX[rt * 64 + (k2off ^ ((rt & 7) << 2))];
#pragma unroll
    for (int t = 0; t < NT; ++t) {
      int col = t * 16 + (lane & 15);
      s16x8 b = *(const s16x8*)&sW[col * 64 + (k2off ^ ((col & 7) << 2))];
      acc[t] = __builtin_amdgcn_mfma_f32_16x16x32_bf16(a, b, acc[t], 0, 0, 0);
    }
  }

  // --- store C (bf16): col=lane&15, row=(lane>>4)*4+reg ---
  const int rbase = row0 + (wid << 4) + ((lane >> 4) << 2);
#pragma unroll
  for (int t = 0; t < NT; ++t) {
    int col = t * 16 + (lane & 15);
#pragma unroll
    for (int r = 0; r < 4; ++r) {
      int row = rbase + r;
      if (row < NN) Y[(size_t)row * FOUT + col] = f2bf(acc[t][r]);
    }
  }
}

// ---------------- fused bucket-gather aggregation (dual-graph) ----------------
// out[i] = relu?( dis_d * ( dis_d*y[i] + sum_e dis[s]*w*y[s] ) + b )

__device__ inline void bf8_fma(float* acc, uint4 v, float w) {
  acc[0] = fmaf(w, bf2f(v.x & 0xffffu), acc[0]);
  acc[1] = fmaf(w, bf2f(v.x >> 16), acc[1]);
  acc[2] = fmaf(w, bf2f(v.y & 0xffffu), acc[2]);
  acc[3] = fmaf(w, bf2f(v.y >> 16), acc[3]);
  acc[4] = fmaf(w, bf2f(v.z & 0xffffu), acc[4]);
  acc[5] = fmaf(w, bf2f(v.z >> 16), acc[5]);
  acc[6] = fmaf(w, bf2f(v.w & 0xffffu), acc[6]);
  acc[7] = fmaf(w, bf2f(v.w >> 16), acc[7]);
}

template<int F, bool RELU, bool OUTBF16>
__global__ __launch_bounds__(256) void k_gather2(
    const int* __restrict__ cnt1, const uint2* __restrict__ bk1,
    const uint* __restrict__ y1, const float* __restrict__ dis1,
    const float* __restrict__ bias1, void* __restrict__ out1,
    const int* __restrict__ cnt2, const uint2* __restrict__ bk2,
    const uint* __restrict__ y2, const float* __restrict__ dis2,
    const float* __restrict__ bias2, void* __restrict__ out2, int nbpg) {
  constexpr int TPN = F / 8;
  constexpr int NPB = 256 / TPN;
  constexpr int RS = F / 2;         // row stride in uints
  const int g = blockIdx.x >= nbpg;
  const int bid = blockIdx.x - (g ? nbpg : 0);
  const int* cnt = g ? cnt2 : cnt1;
  const uint2* bk = g ? bk2 : bk1;
  const uint* y = g ? y2 : y1;
  const float* dis = g ? dis2 : dis1;
  const float* bias = g ? bias2 : bias1;
  void* out = g ? out2 : out1;

  int node = bid * NPB + threadIdx.x / TPN;
  int lane = threadIdx.x % TPN;
  if (node >= NN) return;
  const int c0 = lane * 4;

  const float dd = dis[node];
  float acc[8];
  {
    uint4 sv = *(const uint4*)&y[(size_t)node * RS + c0];
    acc[0] = dd * bf2f(sv.x & 0xffffu); acc[1] = dd * bf2f(sv.x >> 16);
    acc[2] = dd * bf2f(sv.y & 0xffffu); acc[3] = dd * bf2f(sv.y >> 16);
    acc[4] = dd * bf2f(sv.z & 0xffffu); acc[5] = dd * bf2f(sv.z >> 16);
    acc[6] = dd * bf2f(sv.w & 0xffffu); acc[7] = dd * bf2f(sv.w >> 16);
  }
  const uint2* p = &bk[(size_t)node * CAP];
  int m = cnt[node];
  int e = 0;
  for (; e + 1 < m; e += 2) {
    uint2 p0 = p[e], p1 = p[e + 1];
    float w0 = dis[p0.x] * __uint_as_float(p0.y);
    float w1 = dis[p1.x] * __uint_as_float(p1.y);
    uint4 v0 = *(const uint4*)&y[(size_t)p0.x * RS + c0];
    uint4 v1 = *(const uint4*)&y[(size_t)p1.x * RS + c0];
    bf8_fma(acc, v0, w0);
    bf8_fma(acc, v1, w1);
  }
  if (e < m) {
    uint2 p0 = p[e];
    float w0 = dis[p0.x] * __uint_as_float(p0.y);
    uint4 v0 = *(const uint4*)&y[(size_t)p0.x * RS + c0];
    bf8_fma(acc, v0, w0);
  }
  float4 b0 = *(const float4*)&bias[lane * 8];
  float4 b1 = *(const float4*)&bias[lane * 8 + 4];
  float r0[8];
  r0[0] = fmaf(dd, acc[0], b0.x); r0[1] = fmaf(dd, acc[1], b0.y);
  r0[2] = fmaf(dd, acc[2], b0.z); r0[3] = fmaf(dd, acc[3], b0.w);
  r0[4] = fmaf(dd, acc[4], b1.x); r0[5] = fmaf(dd, acc[5], b1.y);
  r0[6] = fmaf(dd, acc[6], b1.z); r0[7] = fmaf(dd, acc[7], b1.w);
  if (RELU) {
#pragma unroll
    for (int j = 0; j < 8; ++j) r0[j] = fmaxf(r0[j], 0.f);
  }
  if (OUTBF16) {
    uint4 o;
    o.x = pack_bf2(r0[0], r0[1]); o.y = pack_bf2(r0[2], r0[3]);
    o.z = pack_bf2(r0[4], r0[5]); o.w = pack_bf2(r0[6], r0[7]);
    *(uint4*)&((uint*)out)[(size_t)node * RS + c0] = o;
  } else {
    float4 o0 = make_float4(r0[0], r0[1], r0[2], r0[3]);
    float4 o1 = make_float4(r0[4], r0[5], r0[6], r0[7]);
    *(float4*)&((float*)out)[(size_t)node * F + lane * 8] = o0;
    *(float4*)&((float*)out)[(size_t)node * F + lane * 8 + 4] = o1;
  }
}

// ---------------- seed cross-injection on bf16 h (numpy last-write-wins) ----------------

__global__ void k_seed_gather(const int* __restrict__ seeds, const uint* __restrict__ h1,
                              const uint* __restrict__ h2, uint* __restrict__ tmpA,
                              uint* __restrict__ tmpB) {
  int i = blockIdx.x;
  int f = threadIdx.x;  // 64 packed uints per row
  int s0 = seeds[i];
  int s1 = seeds[NS + i];
  tmpA[(size_t)i * 64 + f] = h2[(size_t)s1 * 64 + f];
  tmpB[(size_t)i * 64 + f] = h1[(size_t)s0 * 64 + f];
}

__global__ void k_seed_apply(const int* __restrict__ seeds, const int* __restrict__ winA,
                             const int* __restrict__ winB, const uint* __restrict__ tmpA,
                             const uint* __restrict__ tmpB, uint* __restrict__ h1,
                             uint* __restrict__ h2) {
  int i = blockIdx.x;
  int f = threadIdx.x;
  int s0 = seeds[i];
  int s1 = seeds[NS + i];
  if (winA[s0] == i) {
    uint a = h1[(size_t)s0 * 64 + f];
    uint b = tmpA[(size_t)i * 64 + f];
    h1[(size_t)s0 * 64 + f] = pack_bf2(bf2f(a & 0xffffu) + bf2f(b & 0xffffu),
                                       bf2f(a >> 16) + bf2f(b >> 16));
  }
  if (winB[s1] == i) {
    uint a = h2[(size_t)s1 * 64 + f];
    uint b = tmpB[(size_t)i * 64 + f];
    h2[(size_t)s1 * 64 + f] = pack_bf2(bf2f(a & 0xffffu) + bf2f(b & 0xffffu),
                                       bf2f(a >> 16) + bf2f(b >> 16));
  }
}

// ---------------- launcher ----------------

extern "C" void kernel_launch(void* const* d_in, const int* in_sizes, int n_in,
                              void* d_out, int out_size, void* d_ws, size_t ws_size,
                              hipStream_t stream) {
  const float* x1  = (const float*)d_in[0];
  const int*   ei1 = (const int*)d_in[1];
  const float* ew1 = (const float*)d_in[2];
  const float* x2  = (const float*)d_in[3];
  const int*   ei2 = (const int*)d_in[4];
  const float* ew2 = (const float*)d_in[5];
  const int*   sds = (const int*)d_in[6];
  const float* W1  = (const float*)d_in[7];
  const float* b1  = (const float*)d_in[8];
  const float* W2  = (const float*)d_in[9];
  const float* b2  = (const float*)d_in[10];
  const float* W3  = (const float*)d_in[11];
  const float* b3  = (const float*)d_in[12];

  float* o1 = (float*)d_out;
  float* o2 = o1 + (size_t)NN * 64;

  // workspace layout (4-byte units), ~104 MB total
  float* dis  = (float*)d_ws;                   // 2*NN  (dis1 | dis2)
  uint*  yb1  = (uint*)(dis + 2 * NN);          // NN*64 (bf16x2)
  uint*  yb2  = yb1 + (size_t)NN * 64;          // NN*64
  uint*  h1   = yb2 + (size_t)NN * 64;          // NN*64 (bf16x2)
  uint*  h2   = h1 + (size_t)NN * 64;           // NN*64
  int*   winA = (int*)(h2 + (size_t)NN * 64);   // NN
  int*   winB = winA + NN;                      // NN
  int*   cnt1 = winB + NN;                      // NN
  int*   cnt2 = cnt1 + NN;                      // NN
  uint2* bk1  = (uint2*)(cnt2 + NN);            // NN*CAP uint2
  uint2* bk2  = bk1 + (size_t)NN * CAP;         // NN*CAP uint2
  int*   bin_cur = (int*)(bk2 + (size_t)NN * CAP);  // 2*NBIN
  // rec aliases yb1/yb2 (dead until gemm step 5); 2*NBIN*BCAP*8B = 14.5MB < 25.6MB
  uint2* rec  = (uint2*)yb1;
  // tmpA/tmpB alias yb1 (dead between layer-1 gather and layer-2 gemm)
  uint*  tmpA = yb1;                            // NS*64
  uint*  tmpB = tmpA + (size_t)NS * 64;         // NS*64

  const int B = 256;
  const int gN = (NN + B - 1) / B;
  const int ntiles = (NE + TILE - 1) / TILE;

  // 1. init cursors + winners
  k_init<<<gN, B, 0, stream>>>(bin_cur, winA, winB);
  // 2. seed winner scan
  k_win_scan<<<(NS + B - 1) / B, B, 0, stream>>>(sds, winA, winB);
  // 3. pass 1: bin partition, both graphs
  k_part<<<2 * ntiles, B, 0, stream>>>(ei1, ew1, ei2, ew2, bin_cur, rec, ntiles);
  // 4. pass 2: buckets + cnt + dis, both graphs
  k_fill<<<2 * NBIN, B, 0, stream>>>(bin_cur, rec, bk1, bk2, cnt1, cnt2, dis);

  const int gemm_bpg = (NN + 63) / 64;
  const int ga128bpg = (NN * 16 + B - 1) / B;   // TPN=16
  const int ga64bpg  = (NN * 8 + B - 1) / B;    // TPN=8

  // 5. layer-1 GEMMs (f32 in, bf16 out), both graphs
  k_gemm2<128, false><<<2 * gemm_bpg, B, 0, stream>>>(
      x1, x2, W1, W2, (unsigned short*)yb1, (unsigned short*)yb2, gemm_bpg);
  // 6. layer-1 gathers -> h (bf16), both graphs
  k_gather2<128, true, true><<<2 * ga128bpg, B, 0, stream>>>(
      cnt1, bk1, yb1, dis, b1, h1, cnt2, bk2, yb2, dis + NN, b2, h2, ga128bpg);
  // 7-8. seed cross-injection
  k_seed_gather<<<NS, 64, 0, stream>>>(sds, h1, h2, tmpA, tmpB);
  k_seed_apply<<<NS, 64, 0, stream>>>(sds, winA, winB, tmpA, tmpB, h1, h2);
  // 9. layer-2 GEMMs (bf16 in, shared W3), both graphs
  k_gemm2<64, true><<<2 * gemm_bpg, B, 0, stream>>>(
      h1, h2, W3, W3, (unsigned short*)yb1, (unsigned short*)yb2, gemm_bpg);
  // 10. layer-2 gathers -> o (f32), both graphs
  k_gather2<64, false, false><<<2 * ga64bpg, B, 0, stream>>>(
      cnt1, bk1, yb1, dis, b3, o1, cnt2, bk2, yb2, dis + NN, b3, o2, ga64bpg);
}

// Round 10
// 189.973 us; speedup vs baseline: 2.2060x; 1.0376x over previous
//
#include <hip/hip_runtime.h>

#define NN 50000
#define NE 800000
#define NS 5000
#define CAP 64
#define NBIN 196        // ceil(NN/256)
#define BCAP 4608       // per-bin record capacity (mean 4096, +8 sigma)
#define TILE 2048       // edges per k_part block

typedef float f32x4 __attribute__((ext_vector_type(4)));
typedef short s16x8 __attribute__((ext_vector_type(8)));
typedef unsigned int uint;

// ---------------- bf16 helpers ----------------

__device__ inline float bf2f(uint u16) {
  return __uint_as_float(u16 << 16);
}
__device__ inline unsigned short f2bf(float f) {
  uint x = __float_as_uint(f);
  uint r = (x + 0x7fffu + ((x >> 16) & 1u)) >> 16;  // RNE
  return (unsigned short)r;
}
__device__ inline uint pack_bf2(float lo, float hi) {
  return (uint)f2bf(lo) | ((uint)f2bf(hi) << 16);
}

// ---------------- init: bin cursors + winner arrays ----------------

__global__ void k_init(int* __restrict__ bin_cur, int* __restrict__ winA,
                       int* __restrict__ winB) {
  int i = blockIdx.x * blockDim.x + threadIdx.x;
  if (i < NN) { winA[i] = -1; winB[i] = -1; }
  if (i < 2 * NBIN) bin_cur[i] = 0;
}

__global__ void k_win_scan(const int* __restrict__ seeds, int* __restrict__ winA,
                           int* __restrict__ winB) {
  int i = blockIdx.x * blockDim.x + threadIdx.x;
  if (i < NS) {
    atomicMax(&winA[seeds[i]], i);
    atomicMax(&winB[seeds[NS + i]], i);
  }
}

// ---------------- pass 1: bin partition (dual-graph) ----------------
// records: (src | dst_local<<16, w) appended into fixed per-bin regions.

__global__ __launch_bounds__(256) void k_part(const int* __restrict__ ei1,
                                              const float* __restrict__ ew1,
                                              const int* __restrict__ ei2,
                                              const float* __restrict__ ew2,
                                              int* __restrict__ bin_cur,
                                              uint2* __restrict__ rec, int ntiles) {
  __shared__ int hcnt[NBIN];
  __shared__ int hbase[NBIN];
  __shared__ int hoff[NBIN];
  const int g = blockIdx.x >= ntiles;
  const int t0 = (g ? blockIdx.x - ntiles : blockIdx.x) * TILE;
  const int* ei = g ? ei2 : ei1;
  const float* ew = g ? ew2 : ew1;
  for (int i = threadIdx.x; i < NBIN; i += 256) { hcnt[i] = 0; hoff[i] = 0; }
  __syncthreads();

  int dst[8];
#pragma unroll
  for (int k = 0; k < 8; ++k) {
    int e = t0 + k * 256 + threadIdx.x;
    int d = (e < NE) ? ei[NE + e] : -1;
    dst[k] = d;
    if (d >= 0) atomicAdd(&hcnt[d >> 8], 1);
  }
  __syncthreads();
  for (int i = threadIdx.x; i < NBIN; i += 256) {
    int c = hcnt[i];
    hbase[i] = (c > 0) ? atomicAdd(&bin_cur[g * NBIN + i], c) : 0;
  }
  __syncthreads();
#pragma unroll
  for (int k = 0; k < 8; ++k) {
    int e = t0 + k * 256 + threadIdx.x;
    int d = dst[k];
    if (d >= 0) {
      int b = d >> 8;
      int r = atomicAdd(&hoff[b], 1);
      int pos = hbase[b] + r;
      if (pos < BCAP) {
        uint meta = (uint)ei[e] | ((uint)(d & 255) << 16);
        rec[((size_t)(g * NBIN + b)) * BCAP + pos] =
            make_uint2(meta, __float_as_uint(ew[e]));
      }
    }
  }
}

// ---------------- pass 2: bin -> node buckets + cnt + dis ----------------
// one block per (graph, bin): exclusive owner of a 128KB bucket region.

__global__ __launch_bounds__(256) void k_fill(const int* __restrict__ bin_cur,
                                              const uint2* __restrict__ rec,
                                              uint2* __restrict__ bk1,
                                              uint2* __restrict__ bk2,
                                              int* __restrict__ cnt1,
                                              int* __restrict__ cnt2,
                                              float* __restrict__ dis) {
  __shared__ int lcnt[256];
  __shared__ float wsum[256];
  const int b = blockIdx.x % NBIN;
  const int g = blockIdx.x / NBIN;
  uint2* bk = g ? bk2 : bk1;
  int* cnt = g ? cnt2 : cnt1;
  lcnt[threadIdx.x] = 0;
  wsum[threadIdx.x] = 1.0f;   // self-loop weight
  __syncthreads();
  int n = bin_cur[g * NBIN + b];
  if (n > BCAP) n = BCAP;
  const uint2* rbase = &rec[((size_t)(g * NBIN + b)) * BCAP];
  for (int i = threadIdx.x; i < n; i += 256) {
    uint2 rv = rbase[i];
    int dl = rv.x >> 16;
    uint s = rv.x & 0xffffu;
    int r = atomicAdd(&lcnt[dl], 1);
    atomicAdd(&wsum[dl], __uint_as_float(rv.y));
    if (r < CAP) bk[(size_t)((b << 8) + dl) * CAP + r] = make_uint2(s, rv.y);
  }
  __syncthreads();
  int node = (b << 8) + threadIdx.x;
  if (node < NN) {
    int m = lcnt[threadIdx.x];
    if (m > CAP) m = CAP;
    cnt[node] = m;
    dis[g * NN + node] = rsqrtf(wsum[threadIdx.x]);
  }
}

// ---------------- MFMA GEMM (dual-graph): Y(bf16) = X @ W ----------------
// 64 rows/block, 4 waves x 16 rows, whole K=128 staged bf16 in LDS, XOR-swizzled.

template<int FOUT, bool INBF16>
__global__ __launch_bounds__(256) void k_gemm2(const void* __restrict__ X1,
                                               const void* __restrict__ X2,
                                               const float* __restrict__ Wa,
                                               const float* __restrict__ Wb,
                                               unsigned short* __restrict__ Y1,
                                               unsigned short* __restrict__ Y2,
                                               int nbpg) {
  constexpr int NT = FOUT / 16;
  __shared__ uint sX[64 * 64];     // [row][k2] bf16x2, swizzled
  __shared__ uint sW[FOUT * 64];   // [col][k2] bf16x2 (transposed), swizzled
  const int g = blockIdx.x >= nbpg;
  const int bid = blockIdx.x - (g ? nbpg : 0);
  const void* X = g ? X2 : X1;
  const float* W = g ? Wb : Wa;
  unsigned short* Y = g ? Y2 : Y1;
  const int tid = threadIdx.x;
  const int lane = tid & 63;
  const int wid = tid >> 6;
  const int row0 = bid * 64;

  // --- stage X ---
  if (INBF16) {
    const uint* Xu = (const uint*)X;   // row stride 64 uints
#pragma unroll
    for (int it = 0; it < 4; ++it) {
      int idx = it * 256 + tid;        // 64 rows * 16 uint4-slots
      int r = idx >> 4;
      int q = idx & 15;
      int row = row0 + r;
      uint4 v = make_uint4(0u, 0u, 0u, 0u);
      if (row < NN) v = *(const uint4*)&Xu[(size_t)row * 64 + q * 4];
      int sw = (r & 7) << 2;
      sX[r * 64 + ((q * 4 + 0) ^ sw)] = v.x;
      sX[r * 64 + ((q * 4 + 1) ^ sw)] = v.y;
      sX[r * 64 + ((q * 4 + 2) ^ sw)] = v.z;
      sX[r * 64 + ((q * 4 + 3) ^ sw)] = v.w;
    }
  } else {
    const float* Xf = (const float*)X;
#pragma unroll
    for (int it = 0; it < 8; ++it) {
      int idx = it * 256 + tid;        // 64 rows * 32 float4-slots
      int r = idx >> 5;
      int k4 = idx & 31;
      int row = row0 + r;
      float4 v = make_float4(0.f, 0.f, 0.f, 0.f);
      if (row < NN) v = *(const float4*)&Xf[(size_t)row * 128 + k4 * 4];
      int sw = (r & 7) << 2;
      int k2 = k4 * 2;
      sX[r * 64 + ((k2 + 0) ^ sw)] = pack_bf2(v.x, v.y);
      sX[r * 64 + ((k2 + 1) ^ sw)] = pack_bf2(v.z, v.w);
    }
  }

  // --- stage W transposed: sW[col][k2] ---
#pragma unroll
  for (int it = 0; it < FOUT / 16; ++it) {
    int idx = it * 256 + tid;          // 64 k2-slots * FOUT/4 col4-slots
    int k2 = idx / (FOUT / 4);
    int col4 = idx % (FOUT / 4);
    float4 a = *(const float4*)&W[(size_t)(2 * k2) * FOUT + col4 * 4];
    float4 b = *(const float4*)&W[(size_t)(2 * k2 + 1) * FOUT + col4 * 4];
    const float* ap = &a.x;
    const float* bp = &b.x;
#pragma unroll
    for (int c = 0; c < 4; ++c) {
      int col = col4 * 4 + c;
      sW[col * 64 + (k2 ^ ((col & 7) << 2))] = pack_bf2(ap[c], bp[c]);
    }
  }
  __syncthreads();

  // --- MFMA ---
  f32x4 acc[NT];
#pragma unroll
  for (int t = 0; t < NT; ++t) acc[t] = (f32x4)(0.f);

  const int rt = (wid << 4) + (lane & 15);
  const int kg = lane >> 4;
#pragma unroll
  for (int ks = 0; ks < 4; ++ks) {
    int k2off = ks * 16 + kg * 4;
    s16x8 a = *(const s16x8*)&sX[rt * 64 + (k2off ^ ((rt & 7) << 2))];
#pragma unroll
    for (int t = 0; t < NT; ++t) {
      int col = t * 16 + (lane & 15);
      s16x8 b = *(const s16x8*)&sW[col * 64 + (k2off ^ ((col & 7) << 2))];
      acc[t] = __builtin_amdgcn_mfma_f32_16x16x32_bf16(a, b, acc[t], 0, 0, 0);
    }
  }

  // --- store C (bf16): col=lane&15, row=(lane>>4)*4+reg ---
  const int rbase = row0 + (wid << 4) + ((lane >> 4) << 2);
#pragma unroll
  for (int t = 0; t < NT; ++t) {
    int col = t * 16 + (lane & 15);
#pragma unroll
    for (int r = 0; r < 4; ++r) {
      int row = rbase + r;
      if (row < NN) Y[(size_t)row * FOUT + col] = f2bf(acc[t][r]);
    }
  }
}

// ---------------- fused bucket-gather aggregation (dual-graph, 4x ILP) ----------------
// out[i] = relu?( dis_d * ( dis_d*y[i] + sum_e dis[s]*w*y[s] ) + b )

__device__ inline void bf8_fma(float* acc, uint4 v, float w) {
  acc[0] = fmaf(w, bf2f(v.x & 0xffffu), acc[0]);
  acc[1] = fmaf(w, bf2f(v.x >> 16), acc[1]);
  acc[2] = fmaf(w, bf2f(v.y & 0xffffu), acc[2]);
  acc[3] = fmaf(w, bf2f(v.y >> 16), acc[3]);
  acc[4] = fmaf(w, bf2f(v.z & 0xffffu), acc[4]);
  acc[5] = fmaf(w, bf2f(v.z >> 16), acc[5]);
  acc[6] = fmaf(w, bf2f(v.w & 0xffffu), acc[6]);
  acc[7] = fmaf(w, bf2f(v.w >> 16), acc[7]);
}

template<int F, bool RELU, bool OUTBF16>
__global__ __launch_bounds__(256) void k_gather2(
    const int* __restrict__ cnt1, const uint2* __restrict__ bk1,
    const uint* __restrict__ y1, const float* __restrict__ dis1,
    const float* __restrict__ bias1, void* __restrict__ out1,
    const int* __restrict__ cnt2, const uint2* __restrict__ bk2,
    const uint* __restrict__ y2, const float* __restrict__ dis2,
    const float* __restrict__ bias2, void* __restrict__ out2, int nbpg) {
  constexpr int TPN = F / 8;
  constexpr int NPB = 256 / TPN;
  constexpr int RS = F / 2;         // row stride in uints
  const int g = blockIdx.x >= nbpg;
  const int bid = blockIdx.x - (g ? nbpg : 0);
  const int* cnt = g ? cnt2 : cnt1;
  const uint2* bk = g ? bk2 : bk1;
  const uint* y = g ? y2 : y1;
  const float* dis = g ? dis2 : dis1;
  const float* bias = g ? bias2 : bias1;
  void* out = g ? out2 : out1;

  int node = bid * NPB + threadIdx.x / TPN;
  int lane = threadIdx.x % TPN;
  if (node >= NN) return;
  const int c0 = lane * 4;

  const float dd = dis[node];
  float acc[8];
  {
    uint4 sv = *(const uint4*)&y[(size_t)node * RS + c0];
    acc[0] = dd * bf2f(sv.x & 0xffffu); acc[1] = dd * bf2f(sv.x >> 16);
    acc[2] = dd * bf2f(sv.y & 0xffffu); acc[3] = dd * bf2f(sv.y >> 16);
    acc[4] = dd * bf2f(sv.z & 0xffffu); acc[5] = dd * bf2f(sv.z >> 16);
    acc[6] = dd * bf2f(sv.w & 0xffffu); acc[7] = dd * bf2f(sv.w >> 16);
  }
  const uint2* p = &bk[(size_t)node * CAP];
  const int m = cnt[node];
  int e = 0;
  // 4x unrolled: issue all meta + dis + row loads before the FMA block
  for (; e + 3 < m; e += 4) {
    uint2 p0 = p[e], p1 = p[e + 1], p2 = p[e + 2], p3 = p[e + 3];
    float w0 = dis[p0.x] * __uint_as_float(p0.y);
    float w1 = dis[p1.x] * __uint_as_float(p1.y);
    float w2 = dis[p2.x] * __uint_as_float(p2.y);
    float w3 = dis[p3.x] * __uint_as_float(p3.y);
    uint4 v0 = *(const uint4*)&y[(size_t)p0.x * RS + c0];
    uint4 v1 = *(const uint4*)&y[(size_t)p1.x * RS + c0];
    uint4 v2 = *(const uint4*)&y[(size_t)p2.x * RS + c0];
    uint4 v3 = *(const uint4*)&y[(size_t)p3.x * RS + c0];
    bf8_fma(acc, v0, w0);
    bf8_fma(acc, v1, w1);
    bf8_fma(acc, v2, w2);
    bf8_fma(acc, v3, w3);
  }
  if (e + 1 < m) {
    uint2 p0 = p[e], p1 = p[e + 1];
    float w0 = dis[p0.x] * __uint_as_float(p0.y);
    float w1 = dis[p1.x] * __uint_as_float(p1.y);
    uint4 v0 = *(const uint4*)&y[(size_t)p0.x * RS + c0];
    uint4 v1 = *(const uint4*)&y[(size_t)p1.x * RS + c0];
    bf8_fma(acc, v0, w0);
    bf8_fma(acc, v1, w1);
    e += 2;
  }
  if (e < m) {
    uint2 p0 = p[e];
    float w0 = dis[p0.x] * __uint_as_float(p0.y);
    uint4 v0 = *(const uint4*)&y[(size_t)p0.x * RS + c0];
    bf8_fma(acc, v0, w0);
  }
  float4 b0 = *(const float4*)&bias[lane * 8];
  float4 b1 = *(const float4*)&bias[lane * 8 + 4];
  float r0[8];
  r0[0] = fmaf(dd, acc[0], b0.x); r0[1] = fmaf(dd, acc[1], b0.y);
  r0[2] = fmaf(dd, acc[2], b0.z); r0[3] = fmaf(dd, acc[3], b0.w);
  r0[4] = fmaf(dd, acc[4], b1.x); r0[5] = fmaf(dd, acc[5], b1.y);
  r0[6] = fmaf(dd, acc[6], b1.z); r0[7] = fmaf(dd, acc[7], b1.w);
  if (RELU) {
#pragma unroll
    for (int j = 0; j < 8; ++j) r0[j] = fmaxf(r0[j], 0.f);
  }
  if (OUTBF16) {
    uint4 o;
    o.x = pack_bf2(r0[0], r0[1]); o.y = pack_bf2(r0[2], r0[3]);
    o.z = pack_bf2(r0[4], r0[5]); o.w = pack_bf2(r0[6], r0[7]);
    *(uint4*)&((uint*)out)[(size_t)node * RS + c0] = o;
  } else {
    // final f32 output: write-once, keep out of caches (clang ext_vector for NT builtin)
    f32x4 o0 = {r0[0], r0[1], r0[2], r0[3]};
    f32x4 o1 = {r0[4], r0[5], r0[6], r0[7]};
    __builtin_nontemporal_store(o0, (f32x4*)&((float*)out)[(size_t)node * F + lane * 8]);
    __builtin_nontemporal_store(o1, (f32x4*)&((float*)out)[(size_t)node * F + lane * 8 + 4]);
  }
}

// ---------------- seed cross-injection on bf16 h (numpy last-write-wins) ----------------

__global__ void k_seed_gather(const int* __restrict__ seeds, const uint* __restrict__ h1,
                              const uint* __restrict__ h2, uint* __restrict__ tmpA,
                              uint* __restrict__ tmpB) {
  int i = blockIdx.x;
  int f = threadIdx.x;  // 64 packed uints per row
  int s0 = seeds[i];
  int s1 = seeds[NS + i];
  tmpA[(size_t)i * 64 + f] = h2[(size_t)s1 * 64 + f];
  tmpB[(size_t)i * 64 + f] = h1[(size_t)s0 * 64 + f];
}

__global__ void k_seed_apply(const int* __restrict__ seeds, const int* __restrict__ winA,
                             const int* __restrict__ winB, const uint* __restrict__ tmpA,
                             const uint* __restrict__ tmpB, uint* __restrict__ h1,
                             uint* __restrict__ h2) {
  int i = blockIdx.x;
  int f = threadIdx.x;
  int s0 = seeds[i];
  int s1 = seeds[NS + i];
  if (winA[s0] == i) {
    uint a = h1[(size_t)s0 * 64 + f];
    uint b = tmpA[(size_t)i * 64 + f];
    h1[(size_t)s0 * 64 + f] = pack_bf2(bf2f(a & 0xffffu) + bf2f(b & 0xffffu),
                                       bf2f(a >> 16) + bf2f(b >> 16));
  }
  if (winB[s1] == i) {
    uint a = h2[(size_t)s1 * 64 + f];
    uint b = tmpB[(size_t)i * 64 + f];
    h2[(size_t)s1 * 64 + f] = pack_bf2(bf2f(a & 0xffffu) + bf2f(b & 0xffffu),
                                       bf2f(a >> 16) + bf2f(b >> 16));
  }
}

// ---------------- launcher ----------------

extern "C" void kernel_launch(void* const* d_in, const int* in_sizes, int n_in,
                              void* d_out, int out_size, void* d_ws, size_t ws_size,
                              hipStream_t stream) {
  const float* x1  = (const float*)d_in[0];
  const int*   ei1 = (const int*)d_in[1];
  const float* ew1 = (const float*)d_in[2];
  const float* x2  = (const float*)d_in[3];
  const int*   ei2 = (const int*)d_in[4];
  const float* ew2 = (const float*)d_in[5];
  const int*   sds = (const int*)d_in[6];
  const float* W1  = (const float*)d_in[7];
  const float* b1  = (const float*)d_in[8];
  const float* W2  = (const float*)d_in[9];
  const float* b2  = (const float*)d_in[10];
  const float* W3  = (const float*)d_in[11];
  const float* b3  = (const float*)d_in[12];

  float* o1 = (float*)d_out;
  float* o2 = o1 + (size_t)NN * 64;

  // workspace layout (4-byte units), ~104 MB total
  float* dis  = (float*)d_ws;                   // 2*NN  (dis1 | dis2)
  uint*  yb1  = (uint*)(dis + 2 * NN);          // NN*64 (bf16x2)
  uint*  yb2  = yb1 + (size_t)NN * 64;          // NN*64
  uint*  h1   = yb2 + (size_t)NN * 64;          // NN*64 (bf16x2)
  uint*  h2   = h1 + (size_t)NN * 64;           // NN*64
  int*   winA = (int*)(h2 + (size_t)NN * 64);   // NN
  int*   winB = winA + NN;                      // NN
  int*   cnt1 = winB + NN;                      // NN
  int*   cnt2 = cnt1 + NN;                      // NN
  uint2* bk1  = (uint2*)(cnt2 + NN);            // NN*CAP uint2
  uint2* bk2  = bk1 + (size_t)NN * CAP;         // NN*CAP uint2
  int*   bin_cur = (int*)(bk2 + (size_t)NN * CAP);  // 2*NBIN
  // rec aliases yb1/yb2 (dead until gemm step 5); 2*NBIN*BCAP*8B = 14.5MB < 25.6MB
  uint2* rec  = (uint2*)yb1;
  // tmpA/tmpB alias yb1 (dead between layer-1 gather and layer-2 gemm)
  uint*  tmpA = yb1;                            // NS*64
  uint*  tmpB = tmpA + (size_t)NS * 64;         // NS*64

  const int B = 256;
  const int gN = (NN + B - 1) / B;
  const int ntiles = (NE + TILE - 1) / TILE;

  // 1. init cursors + winners
  k_init<<<gN, B, 0, stream>>>(bin_cur, winA, winB);
  // 2. seed winner scan
  k_win_scan<<<(NS + B - 1) / B, B, 0, stream>>>(sds, winA, winB);
  // 3. pass 1: bin partition, both graphs
  k_part<<<2 * ntiles, B, 0, stream>>>(ei1, ew1, ei2, ew2, bin_cur, rec, ntiles);
  // 4. pass 2: buckets + cnt + dis, both graphs
  k_fill<<<2 * NBIN, B, 0, stream>>>(bin_cur, rec, bk1, bk2, cnt1, cnt2, dis);

  const int gemm_bpg = (NN + 63) / 64;
  const int ga128bpg = (NN * 16 + B - 1) / B;   // TPN=16
  const int ga64bpg  = (NN * 8 + B - 1) / B;    // TPN=8

  // 5. layer-1 GEMMs (f32 in, bf16 out), both graphs
  k_gemm2<128, false><<<2 * gemm_bpg, B, 0, stream>>>(
      x1, x2, W1, W2, (unsigned short*)yb1, (unsigned short*)yb2, gemm_bpg);
  // 6. layer-1 gathers -> h (bf16), both graphs
  k_gather2<128, true, true><<<2 * ga128bpg, B, 0, stream>>>(
      cnt1, bk1, yb1, dis, b1, h1, cnt2, bk2, yb2, dis + NN, b2, h2, ga128bpg);
  // 7-8. seed cross-injection
  k_seed_gather<<<NS, 64, 0, stream>>>(sds, h1, h2, tmpA, tmpB);
  k_seed_apply<<<NS, 64, 0, stream>>>(sds, winA, winB, tmpA, tmpB, h1, h2);
  // 9. layer-2 GEMMs (bf16 in, shared W3), both graphs
  k_gemm2<64, true><<<2 * gemm_bpg, B, 0, stream>>>(
      h1, h2, W3, W3, (unsigned short*)yb1, (unsigned short*)yb2, gemm_bpg);
  // 10. layer-2 gathers -> o (f32), both graphs
  k_gather2<64, false, false><<<2 * ga64bpg, B, 0, stream>>>(
      cnt1, bk1, yb1, dis, b3, o1, cnt2, bk2, yb2, dis + NN, b3, o2, ga64bpg);
}